// Round 2
// baseline (182.222 us; speedup 1.0000x reference)
//
#include <hip/hip_runtime.h>

#define N_TRACES 128
#define TLEN 32
#define IN_DIM 64
#define HID 128
#define G4 (4 * HID)            // 512 gate rows
#define BATCH (N_TRACES * TLEN) // 4096
#define HROW 160                // hs row: 8 slices x 20 words (stride-20 => all 32 banks
                                // covered exactly once per ds_read_b128, 16B-aligned)

// ---------- device helpers ----------

__device__ __forceinline__ float fast_sigmoid(float x) {
    return 1.0f / (1.0f + __expf(-x));
}
// tanh(x) = 1 - 2/(e^{2x}+1): stable at both extremes
__device__ __forceinline__ float fast_tanh(float x) {
    return 1.0f - 2.0f / (__expf(2.0f * x) + 1.0f);
}
// sum across 8 consecutive lanes (an "oct"), result in all 8 lanes.
// Verified bit-exact on HW in r6 (absmax 1.2e-7).
__device__ __forceinline__ float oct_reduce(float x) {
    x += __int_as_float(__builtin_amdgcn_update_dpp(
        0, __float_as_int(x), 0xB1 /*quad_perm [1,0,3,2]*/, 0xF, 0xF, true));
    x += __int_as_float(__builtin_amdgcn_update_dpp(
        0, __float_as_int(x), 0x4E /*quad_perm [2,3,0,1]*/, 0xF, 0xF, true));
    x += __int_as_float(__builtin_amdgcn_update_dpp(
        0, __float_as_int(x), 0x141 /*row_half_mirror*/, 0xF, 0xF, true));
    return x;
}

// load 8 gate rows {u0+j+128i : j=0..1, i=0..3}, k-slice [16s,16s+16) of a
// [512][128] matrix. 128 floats/thread (land in AGPRs; r2-r4: no scratch).
// Pin kept to forbid rematerialization.
__device__ __forceinline__ void load_w8(const float* __restrict__ W, int u0, int s,
                                        float (&w)[2][4][16]) {
    #pragma unroll
    for (int j = 0; j < 2; ++j) {
        #pragma unroll
        for (int i = 0; i < 4; ++i) {
            const float* wr = W + (size_t)(u0 + j + 128 * i) * HID + 16 * s;
            #pragma unroll
            for (int q = 0; q < 4; ++q) {
                float4 v = *(const float4*)(wr + 4 * q);
                w[j][i][4 * q + 0] = v.x; w[j][i][4 * q + 1] = v.y;
                w[j][i][4 * q + 2] = v.z; w[j][i][4 * q + 3] = v.w;
            }
        }
    }
    #pragma unroll
    for (int j = 0; j < 2; ++j)
        #pragma unroll
        for (int i = 0; i < 4; ++i)
            #pragma unroll
            for (int k = 0; k < 16; ++k)
                asm volatile("" : "+v"(w[j][i][k]));
}

// acc[j][i] += dot(w[j][i][:], hb[0:16]) ; hb must be 16B aligned.
// 128 FMA, only 4 ds_read_b128 (R=8 halves LDS traffic vs R=4).
__device__ __forceinline__ void matvec8(const float (&w)[2][4][16],
                                        const float* hb, float (&acc)[2][4]) {
    #pragma unroll
    for (int q = 0; q < 4; ++q) {
        float4 v = *(const float4*)(hb + 4 * q);
        float hx[4] = {v.x, v.y, v.z, v.w};
        #pragma unroll
        for (int e = 0; e < 4; ++e) {
            #pragma unroll
            for (int j = 0; j < 2; ++j)
                #pragma unroll
                for (int i = 0; i < 4; ++i)
                    acc[j][i] = fmaf(w[j][i][4 * q + e], hx[e], acc[j][i]);
        }
    }
}

// ---------- input GEMM: out[M][512] = A[M][64] * W[512][64]^T + b1 + b2 ----------
// (unchanged, verified)

template <int K>
__global__ __launch_bounds__(256) void gemm_bt(
    const float* __restrict__ A,
    const float* __restrict__ W,
    const float* __restrict__ b1,
    const float* __restrict__ b2,
    float* __restrict__ out,
    int Nld)
{
    constexpr int LD = 68;
    __shared__ float At[K][LD];
    __shared__ float Wt[K][LD];

    const int tid = threadIdx.x;
    const int m0 = blockIdx.x * 64;
    const int n0 = blockIdx.y * 64;

    const int rot = tid & 3;
    #pragma unroll
    for (int j = 0; j < K / 16; ++j) {
        const int e = 4 * (tid + 256 * j);
        const int row = e / K;
        const int k = e % K;
        float4 va = *(const float4*)(A + (size_t)(m0 + row) * K + k);
        float4 vw = *(const float4*)(W + (size_t)(n0 + row) * K + k);
        float fa[4] = {va.x, va.y, va.z, va.w};
        float fw[4] = {vw.x, vw.y, vw.z, vw.w};
        #pragma unroll
        for (int ii = 0; ii < 4; ++ii) {
            const int i = (ii + rot) & 3;
            At[k + i][row] = fa[i];
            Wt[k + i][row] = fw[i];
        }
    }
    __syncthreads();

    const int tx = tid & 15;
    const int ty = tid >> 4;
    float acc[4][4] = {};

    #pragma unroll 4
    for (int k = 0; k < K; ++k) {
        float4 a = *(const float4*)&At[k][ty * 4];
        float4 w = *(const float4*)&Wt[k][tx * 4];
        acc[0][0] = fmaf(a.x, w.x, acc[0][0]); acc[0][1] = fmaf(a.x, w.y, acc[0][1]);
        acc[0][2] = fmaf(a.x, w.z, acc[0][2]); acc[0][3] = fmaf(a.x, w.w, acc[0][3]);
        acc[1][0] = fmaf(a.y, w.x, acc[1][0]); acc[1][1] = fmaf(a.y, w.y, acc[1][1]);
        acc[1][2] = fmaf(a.y, w.z, acc[1][2]); acc[1][3] = fmaf(a.y, w.w, acc[1][3]);
        acc[2][0] = fmaf(a.z, w.x, acc[2][0]); acc[2][1] = fmaf(a.z, w.y, acc[2][1]);
        acc[2][2] = fmaf(a.z, w.z, acc[2][2]); acc[2][3] = fmaf(a.z, w.w, acc[2][3]);
        acc[3][0] = fmaf(a.w, w.x, acc[3][0]); acc[3][1] = fmaf(a.w, w.y, acc[3][1]);
        acc[3][2] = fmaf(a.w, w.z, acc[3][2]); acc[3][3] = fmaf(a.w, w.w, acc[3][3]);
    }

    float bb[4];
    #pragma unroll
    for (int j = 0; j < 4; ++j) {
        const int n = n0 + tx * 4 + j;
        bb[j] = b1[n] + b2[n];
    }
    #pragma unroll
    for (int i = 0; i < 4; ++i) {
        const int m = m0 + ty * 4 + i;
        float4 v;
        v.x = acc[i][0] + bb[0]; v.y = acc[i][1] + bb[1];
        v.z = acc[i][2] + bb[2]; v.w = acc[i][3] + bb[3];
        *(float4*)(out + (size_t)m * Nld + n0 + tx * 4) = v;
    }
}

// ---------- fused per-trace kernel (512 threads = 8 waves, R=8) ----------
// r7 theory: the per-step cost is dominated by the per-CU-serial LDS pipe
// (read amplification = MACs / rows-per-thread). Thread (ub=tid>>3, s=tid&7)
// owns units {2ub, 2ub+1} x 4 gates, k-slice [16s,16s+16): same 128 FMA and
// 128 weight regs per thread as r5, but HALF the ds_read_b128 traffic
// (32 vs 64 wave-instr/step). xg/h move as float2 (adjacent units). xg for
// step t+1 is prefetched before the step-t barrier (xp is static per phase).
// h storage: h_u at word 20*(u>>4)+(u&15); slice s = words [20s,20s+16):
// the 8 distinct 16B lines of one wavefront ds_read_b128 cover all 32 banks
// exactly once -> conflict-free (measured 0 conflicts in r6).

__global__ __launch_bounds__(512) void fused_trace(
    const float* __restrict__ xproj0, // [4096][512] (incl. both layer-0 biases)
    const float* __restrict__ Whh0,   // [512][128]
    const float* __restrict__ Wih1,   // [512][128]
    const float* __restrict__ bih1,   // [512]
    const float* __restrict__ bhh1,   // [512]
    const float* __restrict__ Whh1,   // [512][128]
    const float* __restrict__ Wlin,   // [128]
    const float* __restrict__ blin,   // [1]
    float* __restrict__ y)            // [4096]
{
    const int trace = blockIdx.x;
    const int tid = threadIdx.x;
    const int ub = tid >> 3;            // unit-pair 0..63
    const int s = tid & 7;              // k-slice 0..7
    const int u0 = 2 * ub;              // first owned unit
    const int hw = 20 * (u0 >> 4) + (u0 & 15); // word of h[u0]; h[u0+1] at hw+1

    __shared__ __align__(16) float hs[TLEN][HROW]; // h1 then h2 (20.5 KB)
    __shared__ __align__(16) float xp[TLEN * G4];  // 64 KB: xproj0 -> xproj1

    float w[2][4][16];

    // ===== Preload xproj0 -> LDS (coalesced float4, conflict-free writes) =====
    const float* xpb = xproj0 + (size_t)trace * TLEN * G4;
    #pragma unroll
    for (int j = 0; j < 8; ++j) {
        const int f4 = j * 512 + tid;
        *(float4*)(&xp[4 * f4]) = *(const float4*)(xpb + 4 * f4);
    }
    load_w8(Whh0, u0, s, w);
    __syncthreads();

    // ===== Phase B: layer-0 recurrence =====
    float2 xgn[4];
    #pragma unroll
    for (int i = 0; i < 4; ++i) xgn[i] = *(const float2*)&xp[128 * i + u0];
    float c0 = 0.0f, c1 = 0.0f;
    #pragma unroll 1
    for (int t = 0; t < TLEN; ++t) {
        float2 xg[4];
        #pragma unroll
        for (int i = 0; i < 4; ++i) xg[i] = xgn[i];

        float acc[2][4] = {};
        if (t > 0) matvec8(w, &hs[t - 1][20 * s], acc);
        #pragma unroll
        for (int j = 0; j < 2; ++j)
            #pragma unroll
            for (int i = 0; i < 4; ++i) acc[j][i] = oct_reduce(acc[j][i]);

        // branch-free: all 8 oct lanes compute identical gates
        const float i0 = fast_sigmoid(acc[0][0] + xg[0].x);
        const float f0 = fast_sigmoid(acc[0][1] + xg[1].x);
        const float g0 = fast_tanh   (acc[0][2] + xg[2].x);
        const float o0 = fast_sigmoid(acc[0][3] + xg[3].x);
        c0 = f0 * c0 + i0 * g0;
        const float h0 = o0 * fast_tanh(c0);
        const float i1 = fast_sigmoid(acc[1][0] + xg[0].y);
        const float f1 = fast_sigmoid(acc[1][1] + xg[1].y);
        const float g1 = fast_tanh   (acc[1][2] + xg[2].y);
        const float o1 = fast_sigmoid(acc[1][3] + xg[3].y);
        c1 = f1 * c1 + i1 * g1;
        const float h1 = o1 * fast_tanh(c1);
        if (s == 0) *(float2*)&hs[t][hw] = make_float2(h0, h1);

        // prefetch next step's gate inputs (xp static in this phase);
        // latency hides under the barrier wait
        if (t < TLEN - 1) {
            #pragma unroll
            for (int i = 0; i < 4; ++i)
                xgn[i] = *(const float2*)&xp[(t + 1) * G4 + 128 * i + u0];
        }
        __syncthreads();
    }

    // ===== Phase C: xp[t] = W_ih1 @ h1(t) + b_ih1 + b_hh1 (no per-t barrier) =====
    load_w8(Wih1, u0, s, w);
    float bi[2][4];
    #pragma unroll
    for (int j = 0; j < 2; ++j)
        #pragma unroll
        for (int i = 0; i < 4; ++i)
            bi[j][i] = bih1[u0 + j + 128 * i] + bhh1[u0 + j + 128 * i];
    #pragma unroll 1
    for (int t = 0; t < TLEN; ++t) {
        float acc[2][4] = {};
        matvec8(w, &hs[t][20 * s], acc);
        #pragma unroll
        for (int j = 0; j < 2; ++j)
            #pragma unroll
            for (int i = 0; i < 4; ++i) acc[j][i] = oct_reduce(acc[j][i]);
        if (s == 0) {
            #pragma unroll
            for (int i = 0; i < 4; ++i)
                *(float2*)&xp[t * G4 + 128 * i + u0] =
                    make_float2(acc[0][i] + bi[0][i], acc[1][i] + bi[1][i]);
        }
    }
    __syncthreads();

    // ===== Phase D: layer-1 recurrence (h2 overwrites hs) =====
    load_w8(Whh1, u0, s, w);
    #pragma unroll
    for (int i = 0; i < 4; ++i) xgn[i] = *(const float2*)&xp[128 * i + u0];
    c0 = 0.0f; c1 = 0.0f;
    #pragma unroll 1
    for (int t = 0; t < TLEN; ++t) {
        float2 xg[4];
        #pragma unroll
        for (int i = 0; i < 4; ++i) xg[i] = xgn[i];

        float acc[2][4] = {};
        if (t > 0) matvec8(w, &hs[t - 1][20 * s], acc);
        #pragma unroll
        for (int j = 0; j < 2; ++j)
            #pragma unroll
            for (int i = 0; i < 4; ++i) acc[j][i] = oct_reduce(acc[j][i]);

        const float i0 = fast_sigmoid(acc[0][0] + xg[0].x);
        const float f0 = fast_sigmoid(acc[0][1] + xg[1].x);
        const float g0 = fast_tanh   (acc[0][2] + xg[2].x);
        const float o0 = fast_sigmoid(acc[0][3] + xg[3].x);
        c0 = f0 * c0 + i0 * g0;
        const float h0 = o0 * fast_tanh(c0);
        const float i1 = fast_sigmoid(acc[1][0] + xg[0].y);
        const float f1 = fast_sigmoid(acc[1][1] + xg[1].y);
        const float g1 = fast_tanh   (acc[1][2] + xg[2].y);
        const float o1 = fast_sigmoid(acc[1][3] + xg[3].y);
        c1 = f1 * c1 + i1 * g1;
        const float h1 = o1 * fast_tanh(c1);
        if (s == 0) *(float2*)&hs[t][hw] = make_float2(h0, h1);

        if (t < TLEN - 1) {
            #pragma unroll
            for (int i = 0; i < 4; ++i)
                xgn[i] = *(const float2*)&xp[(t + 1) * G4 + 128 * i + u0];
        }
        __syncthreads();
    }

    // ===== Phase E: y[trace*32+t] = dot(h2(t), W_lin) + b_lin =====
    if (tid < 256) {
        const int tq = tid >> 3;  // timestep
        const int sq = tid & 7;   // slice: words [20sq,20sq+16) = units 16sq..16sq+15
        float wl[16];
        #pragma unroll
        for (int j = 0; j < 4; ++j) {
            float4 v = *(const float4*)(Wlin + 16 * sq + 4 * j);
            wl[4 * j + 0] = v.x; wl[4 * j + 1] = v.y;
            wl[4 * j + 2] = v.z; wl[4 * j + 3] = v.w;
        }
        const float* hb = &hs[tq][20 * sq];
        float a = 0.f;
        #pragma unroll
        for (int j = 0; j < 4; ++j) {
            float4 v = *(const float4*)(hb + 4 * j);
            a = fmaf(v.x, wl[4 * j + 0], a);
            a = fmaf(v.y, wl[4 * j + 1], a);
            a = fmaf(v.z, wl[4 * j + 2], a);
            a = fmaf(v.w, wl[4 * j + 3], a);
        }
        a = oct_reduce(a);
        if (sq == 0) y[trace * TLEN + tq] = a + blin[0];
    }
}

// ---------- launch ----------

extern "C" void kernel_launch(void* const* d_in, const int* in_sizes, int n_in,
                              void* d_out, int out_size, void* d_ws, size_t ws_size,
                              hipStream_t stream) {
    const float* input = (const float*)d_in[0];  // [4096][64]
    const float* W_ih0 = (const float*)d_in[1];  // [512][64]
    const float* W_hh0 = (const float*)d_in[2];  // [512][128]
    const float* b_ih0 = (const float*)d_in[3];  // [512]
    const float* b_hh0 = (const float*)d_in[4];  // [512]
    const float* W_ih1 = (const float*)d_in[5];  // [512][128]
    const float* W_hh1 = (const float*)d_in[6];  // [512][128]
    const float* b_ih1 = (const float*)d_in[7];  // [512]
    const float* b_hh1 = (const float*)d_in[8];  // [512]
    const float* W_lin = (const float*)d_in[9];  // [1][128]
    const float* b_lin = (const float*)d_in[10]; // [1]
    float* out = (float*)d_out;                  // [4096]

    float* xproj0 = (float*)d_ws; // [4096][512], 8 MB

    dim3 ggrid(BATCH / 64, G4 / 64); // (64, 8)

    // K1: xproj0 = input @ W_ih0^T + b_ih0 + b_hh0 (full-chip GEMM)
    gemm_bt<IN_DIM><<<ggrid, 256, 0, stream>>>(input, W_ih0, b_ih0, b_hh0, xproj0, G4);
    // K2: fused per-trace LSTM0 -> xproj1 -> LSTM1 -> linear readout
    fused_trace<<<N_TRACES, 512, 0, stream>>>(xproj0, W_hh0, W_ih1, b_ih1, b_hh1,
                                              W_hh1, W_lin, b_lin, out);
}

// Round 3
// 165.346 us; speedup vs baseline: 1.1021x; 1.1021x over previous
//
#include <hip/hip_runtime.h>

#define N_TRACES 128
#define TLEN 32
#define IN_DIM 64
#define HID 128
#define G4 (4 * HID)            // 512 gate rows
#define BATCH (N_TRACES * TLEN) // 4096

// ---------- device helpers ----------

__device__ __forceinline__ float fast_sigmoid(float x) {
    return 1.0f / (1.0f + __expf(-x));
}
// tanh(x) = 1 - 2/(e^{2x}+1): stable at both extremes
__device__ __forceinline__ float fast_tanh(float x) {
    return 1.0f - 2.0f / (__expf(2.0f * x) + 1.0f);
}
// sum across the 4 lanes of a quad, result in all 4 lanes
__device__ __forceinline__ float quad_reduce(float x) {
    x += __int_as_float(__builtin_amdgcn_update_dpp(
        0, __float_as_int(x), 0xB1 /*quad_perm [1,0,3,2]*/, 0xF, 0xF, true));
    x += __int_as_float(__builtin_amdgcn_update_dpp(
        0, __float_as_int(x), 0x4E /*quad_perm [2,3,0,1]*/, 0xF, 0xF, true));
    return x;
}

// load 4 gate rows {u+128i}, k-slice [32s,32s+32) of a [512][128] matrix.
// These land in AGPRs (unified file) at VGPR_Count~88 — measured: no scratch,
// no re-fetch. Pin kept to forbid rematerialization.
__device__ __forceinline__ void load_w(const float* __restrict__ W, int u, int s,
                                       float (&w)[4][32]) {
    #pragma unroll
    for (int i = 0; i < 4; ++i) {
        const float* wr = W + (size_t)(u + 128 * i) * HID + 32 * s;
        #pragma unroll
        for (int j = 0; j < 8; ++j) {
            float4 v = *(const float4*)(wr + 4 * j);
            w[i][4 * j + 0] = v.x; w[i][4 * j + 1] = v.y;
            w[i][4 * j + 2] = v.z; w[i][4 * j + 3] = v.w;
        }
    }
    #pragma unroll
    for (int i = 0; i < 4; ++i)
        #pragma unroll
        for (int j = 0; j < 32; ++j)
            asm volatile("" : "+v"(w[i][j]));
}

// acc[i] += dot(w[i][:], hb[0:32]) ; hb must be 16B aligned
__device__ __forceinline__ void matvec_acc(const float (&w)[4][32],
                                           const float* hb, float (&acc)[4]) {
    #pragma unroll
    for (int j = 0; j < 8; ++j) {
        float4 v = *(const float4*)(hb + 4 * j);
        float hx[4] = {v.x, v.y, v.z, v.w};
        #pragma unroll
        for (int e = 0; e < 4; ++e) {
            #pragma unroll
            for (int i = 0; i < 4; ++i)
                acc[i] = fmaf(w[i][4 * j + e], hx[e], acc[i]);
        }
    }
}

// ---------- input GEMM: out[M][512] = A[M][64] * W[512][64]^T + b1 + b2 ----------
// (unchanged, verified)

template <int K>
__global__ __launch_bounds__(256) void gemm_bt(
    const float* __restrict__ A,
    const float* __restrict__ W,
    const float* __restrict__ b1,
    const float* __restrict__ b2,
    float* __restrict__ out,
    int Nld)
{
    constexpr int LD = 68;
    __shared__ float At[K][LD];
    __shared__ float Wt[K][LD];

    const int tid = threadIdx.x;
    const int m0 = blockIdx.x * 64;
    const int n0 = blockIdx.y * 64;

    const int rot = tid & 3;
    #pragma unroll
    for (int j = 0; j < K / 16; ++j) {
        const int e = 4 * (tid + 256 * j);
        const int row = e / K;
        const int k = e % K;
        float4 va = *(const float4*)(A + (size_t)(m0 + row) * K + k);
        float4 vw = *(const float4*)(W + (size_t)(n0 + row) * K + k);
        float fa[4] = {va.x, va.y, va.z, va.w};
        float fw[4] = {vw.x, vw.y, vw.z, vw.w};
        #pragma unroll
        for (int ii = 0; ii < 4; ++ii) {
            const int i = (ii + rot) & 3;
            At[k + i][row] = fa[i];
            Wt[k + i][row] = fw[i];
        }
    }
    __syncthreads();

    const int tx = tid & 15;
    const int ty = tid >> 4;
    float acc[4][4] = {};

    #pragma unroll 4
    for (int k = 0; k < K; ++k) {
        float4 a = *(const float4*)&At[k][ty * 4];
        float4 w = *(const float4*)&Wt[k][tx * 4];
        acc[0][0] = fmaf(a.x, w.x, acc[0][0]); acc[0][1] = fmaf(a.x, w.y, acc[0][1]);
        acc[0][2] = fmaf(a.x, w.z, acc[0][2]); acc[0][3] = fmaf(a.x, w.w, acc[0][3]);
        acc[1][0] = fmaf(a.y, w.x, acc[1][0]); acc[1][1] = fmaf(a.y, w.y, acc[1][1]);
        acc[1][2] = fmaf(a.y, w.z, acc[1][2]); acc[1][3] = fmaf(a.y, w.w, acc[1][3]);
        acc[2][0] = fmaf(a.z, w.x, acc[2][0]); acc[2][1] = fmaf(a.z, w.y, acc[2][1]);
        acc[2][2] = fmaf(a.z, w.z, acc[2][2]); acc[2][3] = fmaf(a.z, w.w, acc[2][3]);
        acc[3][0] = fmaf(a.w, w.x, acc[3][0]); acc[3][1] = fmaf(a.w, w.y, acc[3][1]);
        acc[3][2] = fmaf(a.w, w.z, acc[3][2]); acc[3][3] = fmaf(a.w, w.w, acc[3][3]);
    }

    float bb[4];
    #pragma unroll
    for (int j = 0; j < 4; ++j) {
        const int n = n0 + tx * 4 + j;
        bb[j] = b1[n] + b2[n];
    }
    #pragma unroll
    for (int i = 0; i < 4; ++i) {
        const int m = m0 + ty * 4 + i;
        float4 v;
        v.x = acc[i][0] + bb[0]; v.y = acc[i][1] + bb[1];
        v.z = acc[i][2] + bb[2]; v.w = acc[i][3] + bb[3];
        *(float4*)(out + (size_t)m * Nld + n0 + tx * 4) = v;
    }
}

// ---------- fused per-trace kernel (512 threads, r5 quad structure) ----------
// r8: revert to the proven r5 layout (thread (u=tid>>2, s=tid&3) owns gate rows
// {u+128i}, k-slice [32s,32s+32); quad_reduce = 2 DPP stages). r6/r7's oct
// variants (3-stage reduce, duplicated gate transcendentals) were ~17% slower:
// the step is issue+tail bound, and r5 minimizes both. Two additions:
//  (a) xg prefetch: next step's gate inputs read into regs BEFORE the barrier,
//      removing 4 broadcast LDS reads from the post-barrier critical path.
//  (b) t=0 peel: straight-line loop body (no per-step t>0 branch).
// Math is bit-identical to r5 (expect absmax ~7.6e-6).

__global__ __launch_bounds__(512) void fused_trace(
    const float* __restrict__ xproj0, // [4096][512] (incl. both layer-0 biases)
    const float* __restrict__ Whh0,   // [512][128]
    const float* __restrict__ Wih1,   // [512][128]
    const float* __restrict__ bih1,   // [512]
    const float* __restrict__ bhh1,   // [512]
    const float* __restrict__ Whh1,   // [512][128]
    const float* __restrict__ Wlin,   // [128]
    const float* __restrict__ blin,   // [1]
    float* __restrict__ y)            // [4096]
{
    const int trace = blockIdx.x;
    const int tid = threadIdx.x;
    const int u = tid >> 2;
    const int s = tid & 3;
    const int pu = u + 4 * (u >> 5); // padded word index for unit u

    __shared__ float hs[TLEN][140];     // h1 then h2, padded (p(127)=139)
    __shared__ float xp[TLEN * G4];     // 64 KB: xproj0, then overwritten w/ xproj1

    float w[4][32];

    // ===== Preload xproj0 -> LDS (coalesced float4, conflict-free writes) =====
    const float* xpb = xproj0 + (size_t)trace * TLEN * G4;
    #pragma unroll
    for (int j = 0; j < 8; ++j) {
        const int f4 = j * 512 + tid;
        float4 v = *(const float4*)(xpb + 4 * f4);
        *(float4*)(&xp[4 * f4]) = v;
    }
    load_w(Whh0, u, s, w);
    __syncthreads();

    // ===== Phase B: layer-0 recurrence =====
    float xg[4], xgn[4];
    #pragma unroll
    for (int i = 0; i < 4; ++i) xg[i] = xp[128 * i + u];       // t=0 inputs
    #pragma unroll
    for (int i = 0; i < 4; ++i) xgn[i] = xp[G4 + 128 * i + u]; // t=1 inputs

    float c = 0.0f;
    // t=0 peel: no recurrent matvec (h(-1)=0)
    if (s == 0) {
        const float iv = fast_sigmoid(xg[0]);
        const float fv = fast_sigmoid(xg[1]);
        const float gv = fast_tanh(xg[2]);
        const float ov = fast_sigmoid(xg[3]);
        c = fv * c + iv * gv;
        hs[0][pu] = ov * fast_tanh(c);
    }
    __syncthreads();

    #pragma unroll 1
    for (int t = 1; t < TLEN; ++t) {
        #pragma unroll
        for (int i = 0; i < 4; ++i) xg[i] = xgn[i];

        float acc[4] = {0.f, 0.f, 0.f, 0.f};
        matvec_acc(w, &hs[t - 1][36 * s], acc);
        #pragma unroll
        for (int i = 0; i < 4; ++i) acc[i] = quad_reduce(acc[i]);

        if (s == 0) {
            const float iv = fast_sigmoid(acc[0] + xg[0]);
            const float fv = fast_sigmoid(acc[1] + xg[1]);
            const float gv = fast_tanh(acc[2] + xg[2]);
            const float ov = fast_sigmoid(acc[3] + xg[3]);
            c = fv * c + iv * gv;
            hs[t][pu] = ov * fast_tanh(c);
        }
        // prefetch next step's gate inputs (xp is read-only in this phase);
        // latency hides under the barrier wait
        if (t < TLEN - 1) {
            #pragma unroll
            for (int i = 0; i < 4; ++i)
                xgn[i] = xp[(t + 1) * G4 + 128 * i + u];
        }
        __syncthreads();
    }

    // ===== Phase C: xp[t] = W_ih1 @ h1(t) + b_ih1 + b_hh1 (no per-t barrier) =====
    load_w(Wih1, u, s, w);
    float bi[4] = {0.f, 0.f, 0.f, 0.f};
    if (s == 0) {
        #pragma unroll
        for (int i = 0; i < 4; ++i) bi[i] = bih1[u + 128 * i] + bhh1[u + 128 * i];
    }
    #pragma unroll 1
    for (int t = 0; t < TLEN; ++t) {
        float acc[4] = {0.f, 0.f, 0.f, 0.f};
        matvec_acc(w, &hs[t][36 * s], acc);
        #pragma unroll
        for (int i = 0; i < 4; ++i) acc[i] = quad_reduce(acc[i]);
        if (s == 0) {
            #pragma unroll
            for (int i = 0; i < 4; ++i) xp[t * G4 + 128 * i + u] = acc[i] + bi[i];
        }
    }
    __syncthreads();

    // ===== Phase D: layer-1 recurrence (h2 overwrites hs) =====
    load_w(Whh1, u, s, w);
    #pragma unroll
    for (int i = 0; i < 4; ++i) xg[i] = xp[128 * i + u];       // t=0 inputs
    #pragma unroll
    for (int i = 0; i < 4; ++i) xgn[i] = xp[G4 + 128 * i + u]; // t=1 inputs

    c = 0.0f;
    // t=0 peel
    if (s == 0) {
        const float iv = fast_sigmoid(xg[0]);
        const float fv = fast_sigmoid(xg[1]);
        const float gv = fast_tanh(xg[2]);
        const float ov = fast_sigmoid(xg[3]);
        c = fv * c + iv * gv;
        hs[0][pu] = ov * fast_tanh(c);
    }
    __syncthreads();

    #pragma unroll 1
    for (int t = 1; t < TLEN; ++t) {
        #pragma unroll
        for (int i = 0; i < 4; ++i) xg[i] = xgn[i];

        float acc[4] = {0.f, 0.f, 0.f, 0.f};
        matvec_acc(w, &hs[t - 1][36 * s], acc);
        #pragma unroll
        for (int i = 0; i < 4; ++i) acc[i] = quad_reduce(acc[i]);

        if (s == 0) {
            const float iv = fast_sigmoid(acc[0] + xg[0]);
            const float fv = fast_sigmoid(acc[1] + xg[1]);
            const float gv = fast_tanh(acc[2] + xg[2]);
            const float ov = fast_sigmoid(acc[3] + xg[3]);
            c = fv * c + iv * gv;
            hs[t][pu] = ov * fast_tanh(c);
        }
        if (t < TLEN - 1) {
            #pragma unroll
            for (int i = 0; i < 4; ++i)
                xgn[i] = xp[(t + 1) * G4 + 128 * i + u];
        }
        __syncthreads();
    }

    // ===== Phase E: y[trace*32+t] = dot(h2(t), W_lin) + b_lin =====
    if (tid < 128) {
        const int tq = tid >> 2;
        const int sq = tid & 3;
        float wl[32];
        #pragma unroll
        for (int j = 0; j < 8; ++j) {
            float4 v = *(const float4*)(Wlin + 32 * sq + 4 * j);
            wl[4 * j + 0] = v.x; wl[4 * j + 1] = v.y;
            wl[4 * j + 2] = v.z; wl[4 * j + 3] = v.w;
        }
        const float* hb = &hs[tq][36 * sq];
        float a = 0.f;
        #pragma unroll
        for (int j = 0; j < 8; ++j) {
            float4 v = *(const float4*)(hb + 4 * j);
            a = fmaf(v.x, wl[4 * j + 0], a);
            a = fmaf(v.y, wl[4 * j + 1], a);
            a = fmaf(v.z, wl[4 * j + 2], a);
            a = fmaf(v.w, wl[4 * j + 3], a);
        }
        a = quad_reduce(a);
        if (sq == 0) y[trace * TLEN + tq] = a + blin[0];
    }
}

// ---------- launch ----------

extern "C" void kernel_launch(void* const* d_in, const int* in_sizes, int n_in,
                              void* d_out, int out_size, void* d_ws, size_t ws_size,
                              hipStream_t stream) {
    const float* input = (const float*)d_in[0];  // [4096][64]
    const float* W_ih0 = (const float*)d_in[1];  // [512][64]
    const float* W_hh0 = (const float*)d_in[2];  // [512][128]
    const float* b_ih0 = (const float*)d_in[3];  // [512]
    const float* b_hh0 = (const float*)d_in[4];  // [512]
    const float* W_ih1 = (const float*)d_in[5];  // [512][128]
    const float* W_hh1 = (const float*)d_in[6];  // [512][128]
    const float* b_ih1 = (const float*)d_in[7];  // [512]
    const float* b_hh1 = (const float*)d_in[8];  // [512]
    const float* W_lin = (const float*)d_in[9];  // [1][128]
    const float* b_lin = (const float*)d_in[10]; // [1]
    float* out = (float*)d_out;                  // [4096]

    float* xproj0 = (float*)d_ws; // [4096][512], 8 MB

    dim3 ggrid(BATCH / 64, G4 / 64); // (64, 8)

    // K1: xproj0 = input @ W_ih0^T + b_ih0 + b_hh0 (full-chip GEMM)
    gemm_bt<IN_DIM><<<ggrid, 256, 0, stream>>>(input, W_ih0, b_ih0, b_hh0, xproj0, G4);
    // K2: fused per-trace LSTM0 -> xproj1 -> LSTM1 -> linear readout
    fused_trace<<<N_TRACES, 512, 0, stream>>>(xproj0, W_hh0, W_ih1, b_ih1, b_hh1,
                                              W_hh1, W_lin, b_lin, out);
}